// Round 8
// baseline (1057.909 us; speedup 1.0000x reference)
//
#include <hip/hip_runtime.h>
#include <math.h>

#define NN 100000
#define NE 1600000
#define IN_DIM 512
#define HID 128
#define N_LAYERS 8
#define NB 98               // ceil(NN/1024)
#define PADMAX 3200000      // NE + 15*NN + slack

typedef __attribute__((ext_vector_type(4))) float f32x4;
typedef __attribute__((ext_vector_type(8))) _Float16 h16x8;
typedef __attribute__((ext_vector_type(2))) _Float16 h16x2;

// ---------------- CSR build (rows padded to multiples of 16, col-only) ----------------

__global__ void deg_count_kernel(const int* __restrict__ dst, int* __restrict__ deg) {
    int e = blockIdx.x * blockDim.x + threadIdx.x;
    if (e < NE) atomicAdd(&deg[dst[e]], 1);
}

__global__ void dinv_kernel(const int* __restrict__ deg, float* __restrict__ dinv) {
    int i = blockIdx.x * blockDim.x + threadIdx.x;
    if (i < NN) dinv[i] = rsqrtf((float)(deg[i] + 1));   // +1 self loop
}

__global__ void scan1_kernel(const int* __restrict__ deg, int* __restrict__ bsum) {
    __shared__ int s[16];
    int gi = blockIdx.x * 1024 + threadIdx.x;
    int d = (gi < NN) ? deg[gi] : 0;
    int r = (d + 15) & ~15;                              // padded capacity
    for (int off = 32; off; off >>= 1) r += __shfl_down(r, off, 64);
    if ((threadIdx.x & 63) == 0) s[threadIdx.x >> 6] = r;
    __syncthreads();
    if (threadIdx.x == 0) {
        int t = 0;
        for (int i = 0; i < 16; ++i) t += s[i];
        bsum[blockIdx.x] = t;
    }
}

__global__ void scan2_kernel(const int* __restrict__ bsum, int* __restrict__ boff,
                             int* __restrict__ row_ptr) {
    __shared__ int s[128];
    int tid = threadIdx.x;
    int v = (tid < NB) ? bsum[tid] : 0;
    s[tid] = v;
    __syncthreads();
    for (int off = 1; off < 128; off <<= 1) {
        int t = (tid >= off) ? s[tid - off] : 0;
        __syncthreads();
        s[tid] += t;
        __syncthreads();
    }
    if (tid < NB) boff[tid] = s[tid] - v;   // exclusive
    if (tid == NB - 1) row_ptr[NN] = s[tid];
}

__global__ void scan3_kernel(const int* __restrict__ deg, const int* __restrict__ boff,
                             int* __restrict__ row_ptr, int* __restrict__ cursor) {
    __shared__ int s[1024];
    int tid = threadIdx.x;
    int gi = blockIdx.x * 1024 + tid;
    int d = (gi < NN) ? deg[gi] : 0;
    int v = (d + 15) & ~15;
    s[tid] = v;
    __syncthreads();
    for (int off = 1; off < 1024; off <<= 1) {
        int t = (tid >= off) ? s[tid - off] : 0;
        __syncthreads();
        s[tid] += t;
        __syncthreads();
    }
    if (gi < NN) {
        int o = boff[blockIdx.x] + s[tid] - v;
        row_ptr[gi] = o;
        cursor[gi]  = o;
    }
}

__global__ void pad_kernel(const int* __restrict__ deg, const int* __restrict__ row_ptr,
                           int* __restrict__ col) {
    int i = blockIdx.x * 256 + threadIdx.x;
    if (i < NN) {
        int d = deg[i];
        int s = row_ptr[i] + d;
        int e = row_ptr[i] + ((d + 15) & ~15);
        for (int p = s; p < e; ++p) col[p] = NN;       // sentinel: y[NN] == 0
    }
}

__global__ void fill_kernel(const int* __restrict__ src, const int* __restrict__ dst,
                            int* __restrict__ cursor, int* __restrict__ col) {
    int e = blockIdx.x * blockDim.x + threadIdx.x;
    if (e < NE) {
        int s = src[e], d = dst[e];
        int pos = atomicAdd(&cursor[d], 1);
        col[pos] = s;                                   // single 4B scatter per edge
    }
}

__global__ void zero_sentinel_kernel(_Float16* __restrict__ a, _Float16* __restrict__ b) {
    int t = threadIdx.x;                                // 128 threads
    a[(size_t)NN * HID + t] = (_Float16)0.f;
    b[(size_t)NN * HID + t] = (_Float16)0.f;
}

// ---------------- W prep: fp16 hi/lo split, MFMA B-fragment order ----------------
// B-frag element for (n,kk): B[k = kk*32 + (lane>>4)*8 + j][col = n*16 + (lane&15)]

__global__ void wprep_init_kernel(const float* __restrict__ W,
                                  _Float16* __restrict__ Bhi, _Float16* __restrict__ Blo) {
    int t = blockIdx.x * 256 + threadIdx.x;     // 8 * 16 * 64 = 8192 threads
    if (t >= 8 * 16 * 64) return;
    int lane = t & 63, nkk = t >> 6;
    int n = nkk >> 4, kk = nkk & 15;
    int scol = n * 16 + (lane & 15);
    int sr0 = kk * 32 + (lane >> 4) * 8;
#pragma unroll
    for (int j = 0; j < 8; ++j) {
        float w = W[(size_t)(sr0 + j) * HID + scol];
        _Float16 hi = (_Float16)w;
        _Float16 lo = (_Float16)(w - (float)hi);
        Bhi[(size_t)t * 8 + j] = hi;
        Blo[(size_t)t * 8 + j] = lo;
    }
}

__global__ void wprep_layers_kernel(const float* __restrict__ WL,
                                    _Float16* __restrict__ Bhi, _Float16* __restrict__ Blo) {
    int t = blockIdx.x * 256 + threadIdx.x;     // 8 layers * 8*4*64 = 16384 threads
    if (t >= N_LAYERS * 8 * 4 * 64) return;
    int layer = t >> 11;
    int r = t & 2047;
    int lane = r & 63, nkk = r >> 6;
    int n = nkk >> 2, kk = nkk & 3;
    const float* W = WL + (size_t)layer * HID * HID;
    int scol = n * 16 + (lane & 15);
    int sr0 = kk * 32 + (lane >> 4) * 8;
#pragma unroll
    for (int j = 0; j < 8; ++j) {
        float w = W[(size_t)(sr0 + j) * HID + scol];
        _Float16 hi = (_Float16)w;
        _Float16 lo = (_Float16)(w - (float)hi);
        Bhi[(size_t)t * 8 + j] = hi;
        Blo[(size_t)t * 8 + j] = lo;
    }
}

// ---------------- init projection -> y = fp16(dinv*h0), x0 = fp16(h0) ----------------
// 64 rows/block, 512 thr. Linear 128KB staging span, XOR-swizzled LDS tile.

__device__ inline int xsw(int row, int blk) {      // fp16 offset in [64][512] tile
    return row * 512 + ((blk ^ (row & 7)) << 3);
}

__global__ __launch_bounds__(512) void init_mfma_kernel(
    const float* __restrict__ x, const h16x8* __restrict__ Bhi, const h16x8* __restrict__ Blo,
    const float* __restrict__ b, const float* __restrict__ dinv,
    _Float16* __restrict__ ycur, _Float16* __restrict__ x0h) {
    __shared__ _Float16 xs[64 * 512];           // 64KB, swizzled blocks of 8 fp16
    int t = threadIdx.x;
    int row0 = blockIdx.x * 64;

#pragma unroll
    for (int i = 0; i < 8; ++i) {               // linear 32B chunks: c = t + 512*i
        int c = t + 512 * i;
        int row = c >> 6, blk = c & 63;
        int grow = row0 + row; if (grow >= NN) grow = NN - 1;
        const float* p = x + (size_t)grow * IN_DIM + blk * 8;
        float4 v0 = *(const float4*)p;
        float4 v1 = *(const float4*)(p + 4);
        h16x8 h;
        h[0] = (_Float16)v0.x; h[1] = (_Float16)v0.y;
        h[2] = (_Float16)v0.z; h[3] = (_Float16)v0.w;
        h[4] = (_Float16)v1.x; h[5] = (_Float16)v1.y;
        h[6] = (_Float16)v1.z; h[7] = (_Float16)v1.w;
        *(h16x8*)&xs[xsw(row, blk)] = h;
    }
    __syncthreads();

    int lane = t & 63, wid = t >> 6;            // wave = n-tile
    int rsel = lane & 15, ksel = lane >> 4;

    f32x4 acc[4];
#pragma unroll
    for (int m = 0; m < 4; ++m) acc[m] = (f32x4){0.f, 0.f, 0.f, 0.f};

#pragma unroll
    for (int kk = 0; kk < 16; ++kk) {
        h16x8 bh = Bhi[(wid * 16 + kk) * 64 + lane];
        h16x8 bl = Blo[(wid * 16 + kk) * 64 + lane];
#pragma unroll
        for (int m = 0; m < 4; ++m) {
            h16x8 a = *(const h16x8*)&xs[xsw(m * 16 + rsel, kk * 4 + ksel)];
            acc[m] = __builtin_amdgcn_mfma_f32_16x16x32_f16(a, bh, acc[m], 0, 0, 0);
            acc[m] = __builtin_amdgcn_mfma_f32_16x16x32_f16(a, bl, acc[m], 0, 0, 0);
        }
    }

    int col = wid * 16 + rsel;
    float bias = b[col];
#pragma unroll
    for (int m = 0; m < 4; ++m) {
#pragma unroll
        for (int r = 0; r < 4; ++r) {
            int row = row0 + m * 16 + ksel * 4 + r;
            if (row < NN) {
                float v = acc[m][r] + bias;
                float di = dinv[row];
                ycur[(size_t)row * HID + col] = (_Float16)(di * v);
                x0h[(size_t)row * HID + col]  = (_Float16)v;
            }
        }
    }
}

// ---------------- fused layer: agg(y) -> LDS -> MFMA -> relu/residual -> y_out ----------------
// agg_d = dinv_d * (sum_s y_s + y_d);  h = 0.9*agg + 0.1*x0
// out:  y_out = fp16(dinv_row * relu((1-b)h + b*(h@W)))

__device__ inline int hsw(int row, int blk) {      // fp16 offset in [64][128] tile
    return row * 128 + ((blk ^ (row & 7)) << 3);
}

__global__ __launch_bounds__(512) void fused_layer_kernel(
    const _Float16* __restrict__ y, const _Float16* __restrict__ x0,
    const int* __restrict__ row_ptr, const int* __restrict__ col,
    const float* __restrict__ dinv,
    const h16x8* __restrict__ Bhi, const h16x8* __restrict__ Blo,
    float beta, _Float16* __restrict__ yout) {
    __shared__ _Float16 hs[64 * 128];
    int t = threadIdx.x;
    int lane = t & 63, wid = t >> 6;
    int node0 = blockIdx.x * 64;

    // preload this wave's n-tile B fragments (independent of agg)
    h16x8 bh[4], bl[4];
#pragma unroll
    for (int kk = 0; kk < 4; ++kk) {
        bh[kk] = Bhi[(wid * 4 + kk) * 64 + lane];
        bl[kk] = Blo[(wid * 4 + kk) * 64 + lane];
    }

    // ---- agg phase: wave handles 8 nodes ----
    int g = lane >> 4, q = lane & 15;
    const h16x8* x8 = (const h16x8*)y;
    for (int i = 0; i < 8; ++i) {
        int lrow = wid * 8 + i;
        int node = node0 + lrow;
        if (node < NN) {
            float di = dinv[node];
            h16x8 sv = x8[(size_t)node * 16 + q];
            h16x8 zv = ((const h16x8*)x0)[(size_t)node * 16 + q];
            float acc[8];
#pragma unroll
            for (int j = 0; j < 8; ++j) acc[j] = 0.f;
            int p1 = row_ptr[node + 1];
            for (int p = row_ptr[node]; p < p1; p += 16) {
                int4 c4 = *(const int4*)(col + p + 4 * g);
                h16x8 v0 = x8[(size_t)c4.x * 16 + q];
                h16x8 v1 = x8[(size_t)c4.y * 16 + q];
                h16x8 v2 = x8[(size_t)c4.z * 16 + q];
                h16x8 v3 = x8[(size_t)c4.w * 16 + q];
#pragma unroll
                for (int j = 0; j < 8; ++j)
                    acc[j] += (float)v0[j] + (float)v1[j] + (float)v2[j] + (float)v3[j];
            }
#pragma unroll
            for (int j = 0; j < 8; ++j) {
                acc[j] += __shfl_xor(acc[j], 16, 64);
                acc[j] += __shfl_xor(acc[j], 32, 64);
            }
            if (g == 0) {
                h16x8 o16;
#pragma unroll
                for (int j = 0; j < 8; ++j) {
                    float s = acc[j] + (float)sv[j];       // + self y_d
                    o16[j] = (_Float16)(0.9f * (di * s) + 0.1f * (float)zv[j]);
                }
                *(h16x8*)&hs[hsw(lrow, q)] = o16;
            }
        } else if (g == 0) {
            h16x8 z;
#pragma unroll
            for (int j = 0; j < 8; ++j) z[j] = (_Float16)0.f;
            *(h16x8*)&hs[hsw(lrow, q)] = z;
        }
    }
    __syncthreads();

    // ---- MFMA phase: wave = n-tile wid, 4 m-tiles ----
    int rsel = lane & 15, ksel = lane >> 4;
    f32x4 acc[4];
#pragma unroll
    for (int m = 0; m < 4; ++m) acc[m] = (f32x4){0.f, 0.f, 0.f, 0.f};

#pragma unroll
    for (int m = 0; m < 4; ++m)
#pragma unroll
        for (int kk = 0; kk < 4; ++kk) {
            h16x8 a = *(const h16x8*)&hs[hsw(m * 16 + rsel, kk * 4 + ksel)];
            acc[m] = __builtin_amdgcn_mfma_f32_16x16x32_f16(a, bh[kk], acc[m], 0, 0, 0);
            acc[m] = __builtin_amdgcn_mfma_f32_16x16x32_f16(a, bl[kk], acc[m], 0, 0, 0);
        }

    float ob = 1.0f - beta;
    int colw = wid * 16 + rsel;
#pragma unroll
    for (int m = 0; m < 4; ++m) {
#pragma unroll
        for (int r = 0; r < 4; ++r) {
            int lr = m * 16 + ksel * 4 + r;
            int row = node0 + lr;
            if (row < NN) {
                float h = (float)hs[lr * 128 + (((colw >> 3) ^ (lr & 7)) << 3) + (colw & 7)];
                float v = ob * h + beta * acc[m][r];
                v = v > 0.f ? v : 0.f;
                yout[(size_t)row * HID + colw] = (_Float16)(dinv[row] * v);
            }
        }
    }
}

// ---------------- final projection: out = sqrt(deg+1) * (y . w) + b ----------------

__global__ __launch_bounds__(256) void final16_kernel(
    const _Float16* __restrict__ y, const int* __restrict__ deg,
    const float* __restrict__ Wout, const float* __restrict__ bout,
    float* __restrict__ out) {
    int node = blockIdx.x * 4 + (threadIdx.x >> 6);
    int lane = threadIdx.x & 63;
    h16x2 a = ((const h16x2*)y)[(size_t)node * 64 + lane];
    float2 w = ((const float2*)Wout)[lane];
    float v = (float)a[0] * w.x + (float)a[1] * w.y;
#pragma unroll
    for (int off = 32; off; off >>= 1) v += __shfl_down(v, off, 64);
    if (lane == 0) out[node] = v * sqrtf((float)(deg[node] + 1)) + bout[0];
}

// ---------------- host ----------------

extern "C" void kernel_launch(void* const* d_in, const int* in_sizes, int n_in,
                              void* d_out, int out_size, void* d_ws, size_t ws_size,
                              hipStream_t stream) {
    const float* x_in     = (const float*)d_in[0];
    const int*   ei       = (const int*)d_in[1];
    const float* W_in     = (const float*)d_in[3];
    const float* b_in     = (const float*)d_in[4];
    const float* W_layers = (const float*)d_in[5];
    const float* W_out    = (const float*)d_in[6];
    const float* b_out    = (const float*)d_in[7];
    float* out = (float*)d_out;

    const int* src = ei;
    const int* dst = ei + NE;

    char* ws = (char*)d_ws;
    size_t off = 0;
    auto alloc = [&](size_t bytes) {
        size_t p = off;
        off = (off + bytes + 255) & ~(size_t)255;
        return p;
    };
    int*   deg     = (int*)(ws + alloc((size_t)NN * 4));
    float* dinv    = (float*)(ws + alloc((size_t)NN * 4));
    int*   row_ptr = (int*)(ws + alloc((size_t)(NN + 1) * 4));
    int*   cursor  = (int*)(ws + alloc((size_t)NN * 4));
    int*   bsum    = (int*)(ws + alloc((size_t)NB * 4));
    int*   boff    = (int*)(ws + alloc((size_t)NB * 4));
    int*   col     = (int*)(ws + alloc((size_t)PADMAX * 4));
    _Float16* x0h  = (_Float16*)(ws + alloc((size_t)NN * HID * 2));
    _Float16* bufA = (_Float16*)(ws + alloc((size_t)(NN + 16) * HID * 2));
    _Float16* bufB = (_Float16*)(ws + alloc((size_t)(NN + 16) * HID * 2));
    _Float16* Bhi0 = (_Float16*)(ws + alloc((size_t)IN_DIM * HID * 2));
    _Float16* Blo0 = (_Float16*)(ws + alloc((size_t)IN_DIM * HID * 2));
    _Float16* BhiL = (_Float16*)(ws + alloc((size_t)N_LAYERS * HID * HID * 2));
    _Float16* BloL = (_Float16*)(ws + alloc((size_t)N_LAYERS * HID * HID * 2));

    hipMemsetAsync(deg, 0, (size_t)NN * 4, stream);

    deg_count_kernel<<<NE / 256, 256, 0, stream>>>(dst, deg);
    dinv_kernel<<<(NN + 255) / 256, 256, 0, stream>>>(deg, dinv);
    scan1_kernel<<<NB, 1024, 0, stream>>>(deg, bsum);
    scan2_kernel<<<1, 128, 0, stream>>>(bsum, boff, row_ptr);
    scan3_kernel<<<NB, 1024, 0, stream>>>(deg, boff, row_ptr, cursor);
    pad_kernel<<<(NN + 255) / 256, 256, 0, stream>>>(deg, row_ptr, col);
    fill_kernel<<<NE / 256, 256, 0, stream>>>(src, dst, cursor, col);
    zero_sentinel_kernel<<<1, 128, 0, stream>>>(bufA, bufB);

    wprep_init_kernel<<<32, 256, 0, stream>>>(W_in, Bhi0, Blo0);
    wprep_layers_kernel<<<64, 256, 0, stream>>>(W_layers, BhiL, BloL);

    init_mfma_kernel<<<(NN + 63) / 64, 512, 0, stream>>>(
        x_in, (const h16x8*)Bhi0, (const h16x8*)Blo0, b_in, dinv, bufA, x0h);

    _Float16* cur = bufA;
    _Float16* nxt = bufB;
    for (int l = 0; l < N_LAYERS; ++l) {
        float beta = logf(0.5f / (float)(l + 1) + 1.0f);
        fused_layer_kernel<<<(NN + 63) / 64, 512, 0, stream>>>(
            cur, x0h, row_ptr, col, dinv,
            (const h16x8*)(BhiL + (size_t)l * HID * HID),
            (const h16x8*)(BloL + (size_t)l * HID * HID), beta, nxt);
        _Float16* tmp = cur; cur = nxt; nxt = tmp;
    }

    final16_kernel<<<NN / 4, 256, 0, stream>>>(cur, deg, W_out, b_out, out);
}